// Round 2
// baseline (649.024 us; speedup 1.0000x reference)
//
#include <hip/hip_runtime.h>
#include <hip/hip_bf16.h>
#include <stdint.h>

#define LN_EPS 1e-6f

typedef __bf16 bf16x8 __attribute__((ext_vector_type(8)));
typedef float f32x4 __attribute__((ext_vector_type(4)));

static __device__ __forceinline__ unsigned short f2bf(float f) {
    uint32_t u = __float_as_uint(f);
    uint32_t r = (u + 0x7fffu + ((u >> 16) & 1u)) >> 16;   // RNE
    return (unsigned short)r;
}

// ---------------- Kernel 1: per-row LayerNorm -> bf16 ----------------
// one block per row, H = 4096, 256 threads * 16 elems (float4 loads)
__global__ __launch_bounds__(256) void ln_bf16_kernel(
    const float* __restrict__ x, const float* __restrict__ gamma,
    const float* __restrict__ beta, unsigned short* __restrict__ y, int H)
{
    const int row = blockIdx.x;
    const float* xr = x + (size_t)row * H;
    const int t = threadIdx.x;

    float4 v[4];
    float s = 0.f, ss = 0.f;
#pragma unroll
    for (int i = 0; i < 4; ++i) {
        v[i] = reinterpret_cast<const float4*>(xr)[t + i * 256];
        s  += v[i].x + v[i].y + v[i].z + v[i].w;
        ss += v[i].x * v[i].x + v[i].y * v[i].y + v[i].z * v[i].z + v[i].w * v[i].w;
    }
#pragma unroll
    for (int off = 32; off > 0; off >>= 1) {      // 64-lane wave reduce
        s  += __shfl_down(s, off);
        ss += __shfl_down(ss, off);
    }
    __shared__ float sh_s[4], sh_ss[4];
    const int wid = t >> 6, lane = t & 63;
    if (lane == 0) { sh_s[wid] = s; sh_ss[wid] = ss; }
    __syncthreads();
    s  = sh_s[0] + sh_s[1] + sh_s[2] + sh_s[3];
    ss = sh_ss[0] + sh_ss[1] + sh_ss[2] + sh_ss[3];

    const float mean = s / (float)H;
    const float var  = ss / (float)H - mean * mean;
    const float rstd = rsqrtf(var + LN_EPS);

    unsigned short* yr = y + (size_t)row * H;
#pragma unroll
    for (int i = 0; i < 4; ++i) {
        const int idx = t + i * 256;
        float4 g = reinterpret_cast<const float4*>(gamma)[idx];
        float4 b = reinterpret_cast<const float4*>(beta)[idx];
        uint2 o;
        o.x = (uint32_t)f2bf((v[i].x - mean) * rstd * g.x + b.x)
            | ((uint32_t)f2bf((v[i].y - mean) * rstd * g.y + b.y) << 16);
        o.y = (uint32_t)f2bf((v[i].z - mean) * rstd * g.z + b.z)
            | ((uint32_t)f2bf((v[i].w - mean) * rstd * g.w + b.w) << 16);
        *reinterpret_cast<uint2*>(yr + idx * 4) = o;
    }
}

// ---------------- Kernel 2: W_effT[f][h] = W[h][f] + sum_r A[h][r]*B[r][f] ----------------
// 64x64 tile per block; output transposed (N=F rows, K=H cols) in bf16 so the
// GEMM sees both operands row-major-in-K ("B^T" layout).
__global__ __launch_bounds__(256) void weff_t_kernel(
    const float* __restrict__ Wk,   // [H, F]
    const float* __restrict__ La,   // [H, 32]
    const float* __restrict__ Lb,   // [32, F]
    unsigned short* __restrict__ WT,// [F, H] bf16
    int H, int F)
{
    __shared__ float kt[64][65];
    __shared__ float as_[64][33];
    __shared__ float bs_[32][65];
    const int t = threadIdx.x;
    const int h0 = blockIdx.y * 64;
    const int f0 = blockIdx.x * 64;

    { // kernel tile 64x64 (rows h, cols f)
        const int r = t >> 4, c = (t & 15) * 4;
#pragma unroll
        for (int p = 0; p < 4; ++p) {
            float4 v = *reinterpret_cast<const float4*>(Wk + (size_t)(h0 + r + p * 16) * F + f0 + c);
            kt[r + p * 16][c + 0] = v.x; kt[r + p * 16][c + 1] = v.y;
            kt[r + p * 16][c + 2] = v.z; kt[r + p * 16][c + 3] = v.w;
        }
    }
    { // A tile 64x32
        const int r = t >> 3, c = (t & 7) * 4;
#pragma unroll
        for (int p = 0; p < 2; ++p) {
            float4 v = *reinterpret_cast<const float4*>(La + (size_t)(h0 + r + p * 32) * 32 + c);
            as_[r + p * 32][c + 0] = v.x; as_[r + p * 32][c + 1] = v.y;
            as_[r + p * 32][c + 2] = v.z; as_[r + p * 32][c + 3] = v.w;
        }
    }
    { // B tile 32x64
        const int r = t >> 4, c = (t & 15) * 4;
#pragma unroll
        for (int p = 0; p < 2; ++p) {
            float4 v = *reinterpret_cast<const float4*>(Lb + (size_t)(r + p * 16) * F + f0 + c);
            bs_[r + p * 16][c + 0] = v.x; bs_[r + p * 16][c + 1] = v.y;
            bs_[r + p * 16][c + 2] = v.z; bs_[r + p * 16][c + 3] = v.w;
        }
    }
    __syncthreads();

    const int hl = t & 63;              // each lane owns one h row of the tile
    float areg[32];
#pragma unroll
    for (int r = 0; r < 32; ++r) areg[r] = as_[hl][r];

#pragma unroll
    for (int p = 0; p < 16; ++p) {
        const int fl = (t >> 6) + p * 4;       // wave-uniform column
        float v = kt[hl][fl];
#pragma unroll
        for (int r = 0; r < 32; ++r) v += areg[r] * bs_[r][fl];
        WT[(size_t)(f0 + fl) * H + h0 + hl] = f2bf(v);  // 64 lanes -> 128B coalesced
    }
}

// ---------------- Kernel 3: GEMM out[M,N] = Y[M,K] * WT[N,K]^T + bias ----------------
// m97 structure: 128x128 tile, BK=32, 4 waves 2x2, 4x4 fragments/wave,
// global_load_lds width=16 staging, mfma_f32_16x16x32_bf16.
__global__ __launch_bounds__(256) void gemm_bt_kernel(
    const unsigned short* __restrict__ Y,   // [M,K] bf16
    const unsigned short* __restrict__ WT,  // [N,K] bf16
    const float* __restrict__ bias,         // [N]
    float* __restrict__ out,                // [M,N] f32
    int M, int N, int K)
{
    __shared__ unsigned short As[128 * 32];   // 8 KB
    __shared__ unsigned short Bs[128 * 32];   // 8 KB

    const int t = threadIdx.x;
    const int lane = t & 63;
    const int wid = t >> 6;
    const int wr = wid >> 1, wc = wid & 1;
    const int m0 = blockIdx.y * 128;
    const int n0 = blockIdx.x * 128;

    const char* Yb = (const char*)(Y + (size_t)m0 * K);
    const char* Wb = (const char*)(WT + (size_t)n0 * K);
    const size_t rowbytes = (size_t)K * 2;

    f32x4 acc[4][4];
#pragma unroll
    for (int i = 0; i < 4; ++i)
#pragma unroll
        for (int j = 0; j < 4; ++j) acc[i][j] = (f32x4)(0.f);

    for (int k0 = 0; k0 < K; k0 += 32) {
        __syncthreads();
#pragma unroll
        for (int p = 0; p < 2; ++p) {
            const int o  = (t + p * 256) * 16;   // byte offset in 8KB tile
            const int r  = o >> 6;               // row (64 B per row)
            const int cb = o & 63;               // col byte within row
            __builtin_amdgcn_global_load_lds(
                (const __attribute__((address_space(1))) void*)(Yb + (size_t)r * rowbytes + (size_t)k0 * 2 + cb),
                (__attribute__((address_space(3))) void*)((char*)As + o), 16, 0, 0);
            __builtin_amdgcn_global_load_lds(
                (const __attribute__((address_space(1))) void*)(Wb + (size_t)r * rowbytes + (size_t)k0 * 2 + cb),
                (__attribute__((address_space(3))) void*)((char*)Bs + o), 16, 0, 0);
        }
        __syncthreads();

        bf16x8 af[4], bg[4];
        const int ko = (lane >> 4) * 8;
#pragma unroll
        for (int i = 0; i < 4; ++i)
            af[i] = *reinterpret_cast<const bf16x8*>(&As[(wr * 64 + i * 16 + (lane & 15)) * 32 + ko]);
#pragma unroll
        for (int j = 0; j < 4; ++j)
            bg[j] = *reinterpret_cast<const bf16x8*>(&Bs[(wc * 64 + j * 16 + (lane & 15)) * 32 + ko]);
#pragma unroll
        for (int i = 0; i < 4; ++i)
#pragma unroll
            for (int j = 0; j < 4; ++j)
                acc[i][j] = __builtin_amdgcn_mfma_f32_16x16x32_bf16(af[i], bg[j], acc[i][j], 0, 0, 0);
    }

    // epilogue: D row = (lane>>4)*4 + r (M dim), col = lane&15 (N dim) — m89-verified
#pragma unroll
    for (int j = 0; j < 4; ++j) {
        const int gn = n0 + wc * 64 + j * 16 + (lane & 15);
        const float bj = bias[gn];
#pragma unroll
        for (int i = 0; i < 4; ++i) {
            const int gm = m0 + wr * 64 + i * 16 + ((lane >> 4) << 2);
            float* op = out + (size_t)gm * N + gn;
#pragma unroll
            for (int r = 0; r < 4; ++r)
                op[(size_t)r * N] = acc[i][j][r] + bj;
        }
    }
}

extern "C" void kernel_launch(void* const* d_in, const int* in_sizes, int n_in,
                              void* d_out, int out_size, void* d_ws, size_t ws_size,
                              hipStream_t stream) {
    const float* x     = (const float*)d_in[0];
    const float* scale = (const float*)d_in[1];
    const float* lbias = (const float*)d_in[2];
    const float* Wk    = (const float*)d_in[3];
    const float* La    = (const float*)d_in[4];
    const float* Lb    = (const float*)d_in[5];
    const float* bias  = (const float*)d_in[6];
    float* out = (float*)d_out;

    const int H = in_sizes[1];           // 4096
    const int M = in_sizes[0] / H;       // 8192
    const int F = in_sizes[6];           // 4096

    unsigned short* y  = (unsigned short*)d_ws;                                   // [M,H] bf16, 64 MiB
    unsigned short* WT = (unsigned short*)((char*)d_ws + (size_t)M * H * 2);      // [F,H] bf16, 32 MiB

    ln_bf16_kernel<<<M, 256, 0, stream>>>(x, scale, lbias, y, H);
    weff_t_kernel<<<dim3(F / 64, H / 64), 256, 0, stream>>>(Wk, La, Lb, WT, H, F);
    gemm_bt_kernel<<<dim3(F / 128, M / 128), 256, 0, stream>>>(y, WT, bias, out, M, F, H);
}